// Round 11
// baseline (225.603 us; speedup 1.0000x reference)
//
#include <hip/hip_runtime.h>

// D=128, S=64, K=32 structural. R, V, B, L from in_sizes.
// PERMUTED table layout (exact — dot products are permutation-invariant):
//   Z row (128 B):  byte pos = c*8 + jt  holds fp8(WM[v, d=jt*16+c] * 64),  c<16, jt<8
//   WW8 row (32 B): byte pos = c*2 + j   holds fp8(WW[v, k=j*16+c] * 64),   c<16, j<2
//   Yp[r,pos] = Y[r, (pos&7)*16 + (pos>>3)]
//   pOut[r, sub*8+b] = p[r, k=(b&1)*16+4*sub+(b>>1)]
// M_b dropped: softmax-invariant (exact). T_w/T_b deferred to k4 (exact).
// Streaming traffic uses non-temporal loads/stores so the 8 MB table stays L2-resident.

typedef __attribute__((ext_vector_type(8))) short bf16x8;
typedef __attribute__((ext_vector_type(4))) float f32x4;
typedef __attribute__((ext_vector_type(2))) float vf2;
typedef __attribute__((ext_vector_type(4))) float f4v;
typedef __attribute__((ext_vector_type(4))) unsigned int u4v;

__device__ __forceinline__ unsigned int f2bf_rne(float x) {
  unsigned int u = __float_as_uint(x);
  return (u + 0x7fffu + ((u >> 16) & 1u)) >> 16;
}
__device__ __forceinline__ float4 ldnt_f4(const float* p) {
  f4v v = __builtin_nontemporal_load((const f4v*)p);
  float4 r; r.x = v.x; r.y = v.y; r.z = v.z; r.w = v.w; return r;
}
__device__ __forceinline__ void stnt_f4(float* p, float4 v) {
  f4v t; t.x = v.x; t.y = v.y; t.z = v.z; t.w = v.w;
  __builtin_nontemporal_store(t, (f4v*)p);
}

// ---------------- kA0: one-shot scatter of weights into MFMA fragment-chunk order.
__global__ __launch_bounds__(256) void kA0_pack(
    const float* __restrict__ Mw, const float* __restrict__ Ww,
    uint4* __restrict__ Wpk) {
  int c = blockIdx.x * 256 + threadIdx.x;
  if (c >= 2560) return;
  int cl = c & 63, g = c >> 6;
  int jt = g >> 2, ks = g & 3;
  int n = jt * 16 + (cl & 15);
  int k0 = ks * 32 + (cl >> 4) * 8;
  float v[8];
#pragma unroll
  for (int j = 0; j < 8; ++j) {
    int e = k0 + j;
    v[j] = (n < 128) ? Mw[(size_t)e * 128 + n] : Ww[(size_t)e * 32 + (n - 128)];
  }
  uint4 pk;
  pk.x = f2bf_rne(v[0]) | (f2bf_rne(v[1]) << 16);
  pk.y = f2bf_rne(v[2]) | (f2bf_rne(v[3]) << 16);
  pk.z = f2bf_rne(v[4]) | (f2bf_rne(v[5]) << 16);
  pk.w = f2bf_rne(v[6]) | (f2bf_rne(v[7]) << 16);
  Wpk[c] = pk;
}

// ---------------- kY: permute Y rows into Yp (exact copy, reordered).
__global__ __launch_bounds__(256) void kY_perm(
    const float* __restrict__ Y, float* __restrict__ Yp, int n) {
  int i = blockIdx.x * 256 + threadIdx.x;
  if (i >= n) return;
  int r = i >> 7, pos = i & 127;
  int d = ((pos & 7) << 4) + (pos >> 3);
  Yp[i] = __builtin_nontemporal_load(Y + (size_t)(r << 7) + d);
}

// ---------------- kA: [Z | WW8] = fp8(We @ [Mw|Ww] * 64) via MFMA, permuted stores.
// We is streamed with nt loads; Z/WW8 writes stay in L2 for k3.
__global__ __launch_bounds__(256, 2) void kA_mfma(
    const float* __restrict__ We, const uint4* __restrict__ Wpk,
    unsigned char* __restrict__ Z, unsigned char* __restrict__ WW8, int V) {
  __shared__ uint4 Bs[2560];  // 40 KB
  int t = threadIdx.x;
  int L = t & 63, wid = t >> 6;

#pragma unroll
  for (int q = 0; q < 10; ++q) Bs[t + q * 256] = Wpk[t + q * 256];

  int r0 = blockIdx.x * 64;
  if (r0 > V - 64) r0 = V - 64;
  int rowA = r0 + wid * 16 + (L & 15);
  const float* Arow = We + (size_t)rowA * 128;

  float4 a[8];
#pragma unroll
  for (int ks = 0; ks < 4; ++ks) {
    int koff4 = ks * 8 + (L >> 4) * 2;
    a[ks * 2] = ldnt_f4(Arow + koff4 * 4);
    a[ks * 2 + 1] = ldnt_f4(Arow + koff4 * 4 + 4);
  }
  union { uint4 u; bf16x8 v; } A[4];
#pragma unroll
  for (int ks = 0; ks < 4; ++ks) {
    A[ks].u.x = f2bf_rne(a[ks * 2].x) | (f2bf_rne(a[ks * 2].y) << 16);
    A[ks].u.y = f2bf_rne(a[ks * 2].z) | (f2bf_rne(a[ks * 2].w) << 16);
    A[ks].u.z = f2bf_rne(a[ks * 2 + 1].x) | (f2bf_rne(a[ks * 2 + 1].y) << 16);
    A[ks].u.w = f2bf_rne(a[ks * 2 + 1].z) | (f2bf_rne(a[ks * 2 + 1].w) << 16);
  }
  __syncthreads();

  f32x4 acc[10];
#pragma unroll
  for (int jt = 0; jt < 10; ++jt) acc[jt] = (f32x4){0.f, 0.f, 0.f, 0.f};
#pragma unroll
  for (int ks = 0; ks < 4; ++ks) {
#pragma unroll
    for (int jt = 0; jt < 10; ++jt) {
      union { uint4 u; bf16x8 v; } Bf;
      Bf.u = Bs[(jt * 4 + ks) * 64 + L];
      acc[jt] = __builtin_amdgcn_mfma_f32_16x16x32_bf16(A[ks].v, Bf.v, acc[jt], 0, 0, 0);
    }
  }

  int c = L & 15, q = L >> 4;
#pragma unroll
  for (int i = 0; i < 4; ++i) {
    int orow = r0 + wid * 16 + q * 4 + i;
    int dwA = __builtin_amdgcn_cvt_pk_fp8_f32(acc[0][i] * 64.f, acc[1][i] * 64.f, 0, false);
    dwA = __builtin_amdgcn_cvt_pk_fp8_f32(acc[2][i] * 64.f, acc[3][i] * 64.f, dwA, true);
    int dwB = __builtin_amdgcn_cvt_pk_fp8_f32(acc[4][i] * 64.f, acc[5][i] * 64.f, 0, false);
    dwB = __builtin_amdgcn_cvt_pk_fp8_f32(acc[6][i] * 64.f, acc[7][i] * 64.f, dwB, true);
    uint2 st; st.x = (unsigned int)dwA; st.y = (unsigned int)dwB;
    *(uint2*)(Z + (size_t)orow * 128 + c * 8) = st;
    int dwC = __builtin_amdgcn_cvt_pk_fp8_f32(acc[8][i] * 64.f, acc[9][i] * 64.f, 0, false);
    *(unsigned short*)(WW8 + (size_t)orow * 32 + c * 2) = (unsigned short)dwC;
  }
}

__device__ __forceinline__ vf2 dot_fp8_16_pk(uint4 q, const vf2* y2, vf2 acc) {
#pragma unroll
  for (int w = 0; w < 4; ++w) {
    unsigned int u = (&q.x)[w];
    acc += __builtin_amdgcn_cvt_pk_f32_fp8(u, false) * y2[2 * w];
    acc += __builtin_amdgcn_cvt_pk_f32_fp8(u, true) * y2[2 * w + 1];
  }
  return acc;
}

// ---------------- k3: attention + aspect probs. TWO reviews per wave, permuted
// layouts, nt on streaming hr/Yp/pOut so the table stays L2-resident.
__global__ __launch_bounds__(256, 2) void k3_review(
    const int* __restrict__ hr, const float* __restrict__ Yp,
    const unsigned char* __restrict__ Z, const unsigned char* __restrict__ WW8,
    const float* __restrict__ Wb, float* __restrict__ pOut, int R) {
  int t = threadIdx.x;
  int wv = t >> 6, lane = t & 63;
  int g = lane & 15, sub = lane >> 4;
  int rbase = (blockIdx.x * 4 + wv) * 2;
  int r0 = rbase < R ? rbase : R - 1;
  int r1 = rbase + 1 < R ? rbase + 1 : R - 1;

  int word0 = __builtin_nontemporal_load(hr + (size_t)r0 * 64 + lane);
  int word1 = __builtin_nontemporal_load(hr + (size_t)r1 * 64 + lane);

  // ---- issue ALL random table gathers for both reviews up-front (cached)
  uint4 q0[2][4], q1[2][4];
  uint2 w8[2][4];
#pragma unroll
  for (int p = 0; p < 4; ++p) {
    int wa = __shfl(word0, p * 16 + g);
    int wb = __shfl(word1, p * 16 + g);
    const unsigned char* ba = Z + (size_t)wa * 128 + sub * 32;
    const unsigned char* bb = Z + (size_t)wb * 128 + sub * 32;
    q0[0][p] = *(const uint4*)(ba);
    q1[0][p] = *(const uint4*)(ba + 16);
    w8[0][p] = *(const uint2*)(WW8 + (size_t)wa * 32 + sub * 8);
    q0[1][p] = *(const uint4*)(bb);
    q1[1][p] = *(const uint4*)(bb + 16);
    w8[1][p] = *(const uint2*)(WW8 + (size_t)wb * 32 + sub * 8);
  }
  // Yp fragments (streaming -> nt)
  float4 yv[2][8];
#pragma unroll
  for (int i = 0; i < 8; ++i) {
    yv[0][i] = ldnt_f4(Yp + (size_t)r0 * 128 + (sub * 8 + i) * 4);
    yv[1][i] = ldnt_f4(Yp + (size_t)r1 * 128 + (sub * 8 + i) * 4);
  }
  const float4* Wb4 = (const float4*)Wb;
  float4 wbe = Wb4[sub];
  float4 wbo = Wb4[4 + sub];

#pragma unroll
  for (int v = 0; v < 2; ++v) {
    int r = v ? r1 : r0;
    const vf2* y2 = (const vf2*)yv[v];

    float dxp[4];
#pragma unroll
    for (int p = 0; p < 4; ++p) {
      vf2 a2 = {0.f, 0.f};
      a2 = dot_fp8_16_pk(q0[v][p], y2, a2);
      a2 = dot_fp8_16_pk(q1[v][p], y2 + 8, a2);
      float acc = a2.x + a2.y;
      acc += __shfl_xor(acc, 16);
      acc += __shfl_xor(acc, 32);
      dxp[p] = acc * 0.015625f;
    }
    float dx = dxp[0];
    dx = (sub == 1) ? dxp[1] : dx;
    dx = (sub == 2) ? dxp[2] : dx;
    dx = (sub == 3) ? dxp[3] : dx;

    float m = dx;
#pragma unroll
    for (int off = 32; off; off >>= 1) m = fmaxf(m, __shfl_xor(m, off));
    float ex = __expf(dx - m);
    float sum = ex;
#pragma unroll
    for (int off = 32; off; off >>= 1) sum += __shfl_xor(sum, off);
    float ax = ex / sum;

    float lacc[8];
#pragma unroll
    for (int j = 0; j < 8; ++j) lacc[j] = 0.f;
#pragma unroll
    for (int p = 0; p < 4; ++p) {
      float axp = __shfl(ax, p * 16 + g);
      vf2 a0 = __builtin_amdgcn_cvt_pk_f32_fp8(w8[v][p].x, false);
      vf2 a1 = __builtin_amdgcn_cvt_pk_f32_fp8(w8[v][p].x, true);
      vf2 a2 = __builtin_amdgcn_cvt_pk_f32_fp8(w8[v][p].y, false);
      vf2 a3 = __builtin_amdgcn_cvt_pk_f32_fp8(w8[v][p].y, true);
      lacc[0] += axp * a0.x; lacc[1] += axp * a0.y;
      lacc[2] += axp * a1.x; lacc[3] += axp * a1.y;
      lacc[4] += axp * a2.x; lacc[5] += axp * a2.y;
      lacc[6] += axp * a3.x; lacc[7] += axp * a3.y;
    }
#pragma unroll
    for (int off = 8; off; off >>= 1) {
#pragma unroll
      for (int j = 0; j < 8; ++j) lacc[j] += __shfl_xor(lacc[j], off);
    }
    lacc[0] = lacc[0] * 0.015625f + wbe.x; lacc[1] = lacc[1] * 0.015625f + wbo.x;
    lacc[2] = lacc[2] * 0.015625f + wbe.y; lacc[3] = lacc[3] * 0.015625f + wbo.y;
    lacc[4] = lacc[4] * 0.015625f + wbe.z; lacc[5] = lacc[5] * 0.015625f + wbo.z;
    lacc[6] = lacc[6] * 0.015625f + wbe.w; lacc[7] = lacc[7] * 0.015625f + wbo.w;

    float mk = lacc[0];
#pragma unroll
    for (int j = 1; j < 8; ++j) mk = fmaxf(mk, lacc[j]);
    mk = fmaxf(mk, __shfl_xor(mk, 16));
    mk = fmaxf(mk, __shfl_xor(mk, 32));
    float ek[8], sk = 0.f;
#pragma unroll
    for (int j = 0; j < 8; ++j) { ek[j] = __expf(lacc[j] - mk); sk += ek[j]; }
    sk += __shfl_xor(sk, 16);
    sk += __shfl_xor(sk, 32);
    float inv = 1.0f / sk;

    if (g == 0) {
      float4 o0, o1;
      o0.x = ek[0] * inv; o0.y = ek[1] * inv; o0.z = ek[2] * inv; o0.w = ek[3] * inv;
      o1.x = ek[4] * inv; o1.y = ek[5] * inv; o1.z = ek[6] * inv; o1.w = ek[7] * inv;
      float* dst = pOut + (size_t)r * 32 + sub * 8;
      stnt_f4(dst, o0);
      stnt_f4(dst + 4, o1);
    }
  }
}

// ---------------- k4: pool permuted p over contiguous segments, apply Tw/Tb, dot.
__global__ __launch_bounds__(256) void k4_final(
    const float* __restrict__ p, const int* __restrict__ uidx,
    const int* __restrict__ iidx, const int* __restrict__ user,
    const int* __restrict__ item, const float* __restrict__ uemb,
    const float* __restrict__ iemb, const float* __restrict__ Tw,
    const float* __restrict__ Tb, const float* __restrict__ avg,
    float* __restrict__ out, int B, int per) {
  int t = threadIdx.x;
  int w = t >> 6, lane = t & 63;
  int b = blockIdx.x * 4 + w;
  if (b >= B) return;

  int idx = lane & 31;
  const int* sidx = (lane < 32) ? uidx : iidx;
  float pbar = 0.f;
  int base = b * per;
  for (int j = 0; j < per; ++j) {
    int id = sidx[base + j];
    pbar += p[(size_t)id * 32 + idx];
  }
  pbar *= 1.0f / (float)per;

  const float2* T2 = (const float2*)Tw;
  float2 tb2 = ((const float2*)Tb)[lane];
  float2 ua = tb2, ia = tb2;
#pragma unroll 8
  for (int kk = 0; kk < 32; ++kk) {
    int ka = ((kk & 1) << 4) + ((kk >> 3) << 2) + ((kk & 7) >> 1);
    float pu = __shfl(pbar, kk);
    float pi = __shfl(pbar, 32 + kk);
    float2 tv = T2[ka * 64 + lane];
    ua.x += pu * tv.x; ua.y += pu * tv.y;
    ia.x += pi * tv.x; ia.y += pi * tv.y;
  }
  float part = ua.x * ia.x + ua.y * ia.y;
  float2 uf = ((const float2*)uemb)[(size_t)user[b] * 64 + lane];
  float2 itf = ((const float2*)iemb)[(size_t)item[b] * 64 + lane];
  part += uf.x * itf.x + uf.y * itf.y;
#pragma unroll
  for (int off = 32; off; off >>= 1) part += __shfl_xor(part, off);
  if (lane == 0) out[b] = part + avg[0];
}

extern "C" void kernel_launch(void* const* d_in, const int* in_sizes, int n_in,
                              void* d_out, int out_size, void* d_ws, size_t ws_size,
                              hipStream_t stream) {
  const int*   user = (const int*)d_in[0];
  const int*   item = (const int*)d_in[1];
  const int*   hr   = (const int*)d_in[2];
  const float* Y    = (const float*)d_in[3];
  const int*   uhi  = (const int*)d_in[4];
  const int*   ihi  = (const int*)d_in[6];
  const float* We   = (const float*)d_in[8];
  const float* Mw   = (const float*)d_in[9];
  // d_in[10]: M_b — softmax-invariant, dropped
  const float* Ww   = (const float*)d_in[11];
  const float* Wb   = (const float*)d_in[12];
  const float* Tw   = (const float*)d_in[13];
  const float* Tb   = (const float*)d_in[14];
  const float* Ue   = (const float*)d_in[15];
  const float* Ie   = (const float*)d_in[16];
  const float* avg  = (const float*)d_in[17];

  int B = in_sizes[0];
  int R = in_sizes[3] / 128;
  int V = in_sizes[8] / 128;
  int L = in_sizes[4];
  int per = L / B;

  unsigned char* ws = (unsigned char*)d_ws;
  uint4* Wpk = (uint4*)ws;                               // 40 KB
  unsigned char* Z   = ws + 40960;                       // V*128
  unsigned char* WW8 = Z + (size_t)V * 128;              // V*32
  float* Yp   = (float*)(WW8 + (size_t)V * 32);          // R*128 floats
  float* pbuf = Yp + (size_t)R * 128;                    // R*32 floats
  float* out = (float*)d_out;

  kA0_pack<<<10, 256, 0, stream>>>(Mw, Ww, Wpk);
  kY_perm<<<(R * 128 + 255) / 256, 256, 0, stream>>>(Y, Yp, R * 128);
  kA_mfma<<<(V + 63) / 64, 256, 0, stream>>>(We, Wpk, Z, WW8, V);
  k3_review<<<(R + 7) / 8, 256, 0, stream>>>(hr, Yp, Z, WW8, Wb, pbuf, R);
  k4_final<<<(B + 3) / 4, 256, 0, stream>>>(pbuf, uhi, ihi, user, item, Ue, Ie,
                                            Tw, Tb, avg, out, B, per);
}

// Round 12
// 215.826 us; speedup vs baseline: 1.0453x; 1.0453x over previous
//
#include <hip/hip_runtime.h>

// D=128, S=64, K=32 structural. R, V, B, L from in_sizes.
// PERMUTED table layout (exact — dot products are permutation-invariant):
//   fp4 path: Z row (64 B): nibble pos = c*8 + jt holds fp4(WM[v,d=jt*16+c]*64)
//   fp8 path: Z row (128 B): byte  pos = c*8 + jt holds fp8(WM[v,d=jt*16+c]*64)
//   (same pos->d map: d = (pos&7)*16 + (pos>>3) — kY/k4 identical for both)
//   WW8 row (32 B): byte pos = c*2 + j holds fp8(WW[v, k=j*16+c] * 64)
//   Yp[r,pos] = Y[r, (pos&7)*16 + (pos>>3)]
//   pOut[r, sub*8+b] = p[r, k=(b&1)*16+4*sub+(b>>1)]
// M_b dropped: softmax-invariant (exact). T_w/T_b deferred to k4 (exact).

#if __has_builtin(__builtin_amdgcn_cvt_scalef32_pk_f32_fp4) && \
    __has_builtin(__builtin_amdgcn_cvt_scalef32_pk_fp4_f32)
#define HAVE_FP4 1
#else
#define HAVE_FP4 0
#endif

typedef __attribute__((ext_vector_type(8))) short bf16x8;
typedef __attribute__((ext_vector_type(4))) float f32x4;
typedef __attribute__((ext_vector_type(2))) float vf2;
typedef __attribute__((ext_vector_type(4))) float f4v;

__device__ __forceinline__ unsigned int f2bf_rne(float x) {
  unsigned int u = __float_as_uint(x);
  return (u + 0x7fffu + ((u >> 16) & 1u)) >> 16;
}
__device__ __forceinline__ float4 ldnt_f4(const float* p) {
  f4v v = __builtin_nontemporal_load((const f4v*)p);
  float4 r; r.x = v.x; r.y = v.y; r.z = v.z; r.w = v.w; return r;
}
__device__ __forceinline__ void stnt_f4(float* p, float4 v) {
  f4v t; t.x = v.x; t.y = v.y; t.z = v.z; t.w = v.w;
  __builtin_nontemporal_store(t, (f4v*)p);
}

// ---------------- kA0: one-shot scatter of weights into MFMA fragment-chunk order.
__global__ __launch_bounds__(256) void kA0_pack(
    const float* __restrict__ Mw, const float* __restrict__ Ww,
    uint4* __restrict__ Wpk) {
  int c = blockIdx.x * 256 + threadIdx.x;
  if (c >= 2560) return;
  int cl = c & 63, g = c >> 6;
  int jt = g >> 2, ks = g & 3;
  int n = jt * 16 + (cl & 15);
  int k0 = ks * 32 + (cl >> 4) * 8;
  float v[8];
#pragma unroll
  for (int j = 0; j < 8; ++j) {
    int e = k0 + j;
    v[j] = (n < 128) ? Mw[(size_t)e * 128 + n] : Ww[(size_t)e * 32 + (n - 128)];
  }
  uint4 pk;
  pk.x = f2bf_rne(v[0]) | (f2bf_rne(v[1]) << 16);
  pk.y = f2bf_rne(v[2]) | (f2bf_rne(v[3]) << 16);
  pk.z = f2bf_rne(v[4]) | (f2bf_rne(v[5]) << 16);
  pk.w = f2bf_rne(v[6]) | (f2bf_rne(v[7]) << 16);
  Wpk[c] = pk;
}

// ---------------- kY: permute Y rows into Yp (exact copy, reordered).
__global__ __launch_bounds__(256) void kY_perm(
    const float* __restrict__ Y, float* __restrict__ Yp, int n) {
  int i = blockIdx.x * 256 + threadIdx.x;
  if (i >= n) return;
  int r = i >> 7, pos = i & 127;
  int d = ((pos & 7) << 4) + (pos >> 3);
  Yp[i] = __builtin_nontemporal_load(Y + (size_t)(r << 7) + d);
}

// ---------------- kA: [Z | WW8] = quant(We @ [Mw|Ww] * 64) via MFMA.
__global__ __launch_bounds__(256, 2) void kA_mfma(
    const float* __restrict__ We, const uint4* __restrict__ Wpk,
    unsigned char* __restrict__ Z, unsigned char* __restrict__ WW8, int V) {
  __shared__ uint4 Bs[2560];  // 40 KB
  int t = threadIdx.x;
  int L = t & 63, wid = t >> 6;

#pragma unroll
  for (int q = 0; q < 10; ++q) Bs[t + q * 256] = Wpk[t + q * 256];

  int r0 = blockIdx.x * 64;
  if (r0 > V - 64) r0 = V - 64;
  int rowA = r0 + wid * 16 + (L & 15);
  const float* Arow = We + (size_t)rowA * 128;

  float4 a[8];
#pragma unroll
  for (int ks = 0; ks < 4; ++ks) {
    int koff4 = ks * 8 + (L >> 4) * 2;
    a[ks * 2] = ldnt_f4(Arow + koff4 * 4);
    a[ks * 2 + 1] = ldnt_f4(Arow + koff4 * 4 + 4);
  }
  union { uint4 u; bf16x8 v; } A[4];
#pragma unroll
  for (int ks = 0; ks < 4; ++ks) {
    A[ks].u.x = f2bf_rne(a[ks * 2].x) | (f2bf_rne(a[ks * 2].y) << 16);
    A[ks].u.y = f2bf_rne(a[ks * 2].z) | (f2bf_rne(a[ks * 2].w) << 16);
    A[ks].u.z = f2bf_rne(a[ks * 2 + 1].x) | (f2bf_rne(a[ks * 2 + 1].y) << 16);
    A[ks].u.w = f2bf_rne(a[ks * 2 + 1].z) | (f2bf_rne(a[ks * 2 + 1].w) << 16);
  }
  __syncthreads();

  f32x4 acc[10];
#pragma unroll
  for (int jt = 0; jt < 10; ++jt) acc[jt] = (f32x4){0.f, 0.f, 0.f, 0.f};
#pragma unroll
  for (int ks = 0; ks < 4; ++ks) {
#pragma unroll
    for (int jt = 0; jt < 10; ++jt) {
      union { uint4 u; bf16x8 v; } Bf;
      Bf.u = Bs[(jt * 4 + ks) * 64 + L];
      acc[jt] = __builtin_amdgcn_mfma_f32_16x16x32_bf16(A[ks].v, Bf.v, acc[jt], 0, 0, 0);
    }
  }

  int c = L & 15, q = L >> 4;
#pragma unroll
  for (int i = 0; i < 4; ++i) {
    int orow = r0 + wid * 16 + q * 4 + i;
#if HAVE_FP4
    unsigned int dz;
    dz = (unsigned int)__builtin_amdgcn_cvt_scalef32_pk_fp4_f32(0u, acc[0][i] * 64.f, acc[1][i] * 64.f, 1.0f, 0);
    dz = (unsigned int)__builtin_amdgcn_cvt_scalef32_pk_fp4_f32(dz, acc[2][i] * 64.f, acc[3][i] * 64.f, 1.0f, 1);
    dz = (unsigned int)__builtin_amdgcn_cvt_scalef32_pk_fp4_f32(dz, acc[4][i] * 64.f, acc[5][i] * 64.f, 1.0f, 2);
    dz = (unsigned int)__builtin_amdgcn_cvt_scalef32_pk_fp4_f32(dz, acc[6][i] * 64.f, acc[7][i] * 64.f, 1.0f, 3);
    *(unsigned int*)(Z + (size_t)orow * 64 + c * 4) = dz;
#else
    int dwA = __builtin_amdgcn_cvt_pk_fp8_f32(acc[0][i] * 64.f, acc[1][i] * 64.f, 0, false);
    dwA = __builtin_amdgcn_cvt_pk_fp8_f32(acc[2][i] * 64.f, acc[3][i] * 64.f, dwA, true);
    int dwB = __builtin_amdgcn_cvt_pk_fp8_f32(acc[4][i] * 64.f, acc[5][i] * 64.f, 0, false);
    dwB = __builtin_amdgcn_cvt_pk_fp8_f32(acc[6][i] * 64.f, acc[7][i] * 64.f, dwB, true);
    uint2 st; st.x = (unsigned int)dwA; st.y = (unsigned int)dwB;
    *(uint2*)(Z + (size_t)orow * 128 + c * 8) = st;
#endif
    int dwC = __builtin_amdgcn_cvt_pk_fp8_f32(acc[8][i] * 64.f, acc[9][i] * 64.f, 0, false);
    *(unsigned short*)(WW8 + (size_t)orow * 32 + c * 2) = (unsigned short)dwC;
  }
}

__device__ __forceinline__ vf2 dot_fp8_16_pk(uint4 q, const vf2* y2, vf2 acc) {
#pragma unroll
  for (int w = 0; w < 4; ++w) {
    unsigned int u = (&q.x)[w];
    acc += __builtin_amdgcn_cvt_pk_f32_fp8(u, false) * y2[2 * w];
    acc += __builtin_amdgcn_cvt_pk_f32_fp8(u, true) * y2[2 * w + 1];
  }
  return acc;
}

#if HAVE_FP4
// dot of one fp4 dword (8 values) against 4 consecutive float2.
__device__ __forceinline__ vf2 dot_fp4_dw(unsigned int u, const vf2* y2, vf2 acc) {
  acc += ((vf2)__builtin_amdgcn_cvt_scalef32_pk_f32_fp4(u, 1.0f, 0)) * y2[0];
  acc += ((vf2)__builtin_amdgcn_cvt_scalef32_pk_f32_fp4(u, 1.0f, 1)) * y2[1];
  acc += ((vf2)__builtin_amdgcn_cvt_scalef32_pk_f32_fp4(u, 1.0f, 2)) * y2[2];
  acc += ((vf2)__builtin_amdgcn_cvt_scalef32_pk_f32_fp4(u, 1.0f, 3)) * y2[3];
  return acc;
}
#endif

// ---------------- k3: attention + aspect probs. TWO reviews per wave.
__global__ __launch_bounds__(256, 2) void k3_review(
    const int* __restrict__ hr, const float* __restrict__ Yp,
    const unsigned char* __restrict__ Z, const unsigned char* __restrict__ WW8,
    const float* __restrict__ Wb, float* __restrict__ pOut, int R) {
  int t = threadIdx.x;
  int wv = t >> 6, lane = t & 63;
  int g = lane & 15, sub = lane >> 4;
  int rbase = (blockIdx.x * 4 + wv) * 2;
  int r0 = rbase < R ? rbase : R - 1;
  int r1 = rbase + 1 < R ? rbase + 1 : R - 1;

  int word0 = __builtin_nontemporal_load(hr + (size_t)r0 * 64 + lane);
  int word1 = __builtin_nontemporal_load(hr + (size_t)r1 * 64 + lane);

  // ---- issue ALL random table gathers for both reviews up-front
#if HAVE_FP4
  uint4 qz[2][4];
#else
  uint4 q0[2][4], q1[2][4];
#endif
  uint2 w8[2][4];
#pragma unroll
  for (int p = 0; p < 4; ++p) {
    int wa = __shfl(word0, p * 16 + g);
    int wb = __shfl(word1, p * 16 + g);
#if HAVE_FP4
    qz[0][p] = *(const uint4*)(Z + (size_t)wa * 64 + sub * 16);
    qz[1][p] = *(const uint4*)(Z + (size_t)wb * 64 + sub * 16);
#else
    const unsigned char* ba = Z + (size_t)wa * 128 + sub * 32;
    const unsigned char* bb = Z + (size_t)wb * 128 + sub * 32;
    q0[0][p] = *(const uint4*)(ba);
    q1[0][p] = *(const uint4*)(ba + 16);
    q0[1][p] = *(const uint4*)(bb);
    q1[1][p] = *(const uint4*)(bb + 16);
#endif
    w8[0][p] = *(const uint2*)(WW8 + (size_t)wa * 32 + sub * 8);
    w8[1][p] = *(const uint2*)(WW8 + (size_t)wb * 32 + sub * 8);
  }
  float4 yv[2][8];
#pragma unroll
  for (int i = 0; i < 8; ++i) {
    yv[0][i] = ldnt_f4(Yp + (size_t)r0 * 128 + (sub * 8 + i) * 4);
    yv[1][i] = ldnt_f4(Yp + (size_t)r1 * 128 + (sub * 8 + i) * 4);
  }
  const float4* Wb4 = (const float4*)Wb;
  float4 wbe = Wb4[sub];
  float4 wbo = Wb4[4 + sub];

#pragma unroll
  for (int v = 0; v < 2; ++v) {
    int r = v ? r1 : r0;
    const vf2* y2 = (const vf2*)yv[v];

    float dxp[4];
#pragma unroll
    for (int p = 0; p < 4; ++p) {
      vf2 a2 = {0.f, 0.f};
#if HAVE_FP4
      a2 = dot_fp4_dw(qz[v][p].x, y2, a2);
      a2 = dot_fp4_dw(qz[v][p].y, y2 + 4, a2);
      a2 = dot_fp4_dw(qz[v][p].z, y2 + 8, a2);
      a2 = dot_fp4_dw(qz[v][p].w, y2 + 12, a2);
#else
      a2 = dot_fp8_16_pk(q0[v][p], y2, a2);
      a2 = dot_fp8_16_pk(q1[v][p], y2 + 8, a2);
#endif
      float acc = a2.x + a2.y;
      acc += __shfl_xor(acc, 16);
      acc += __shfl_xor(acc, 32);
      dxp[p] = acc * 0.015625f;
    }
    float dx = dxp[0];
    dx = (sub == 1) ? dxp[1] : dx;
    dx = (sub == 2) ? dxp[2] : dx;
    dx = (sub == 3) ? dxp[3] : dx;

    float m = dx;
#pragma unroll
    for (int off = 32; off; off >>= 1) m = fmaxf(m, __shfl_xor(m, off));
    float ex = __expf(dx - m);
    float sum = ex;
#pragma unroll
    for (int off = 32; off; off >>= 1) sum += __shfl_xor(sum, off);
    float ax = ex / sum;

    float lacc[8];
#pragma unroll
    for (int j = 0; j < 8; ++j) lacc[j] = 0.f;
#pragma unroll
    for (int p = 0; p < 4; ++p) {
      float axp = __shfl(ax, p * 16 + g);
      vf2 a0 = __builtin_amdgcn_cvt_pk_f32_fp8(w8[v][p].x, false);
      vf2 a1 = __builtin_amdgcn_cvt_pk_f32_fp8(w8[v][p].x, true);
      vf2 a2 = __builtin_amdgcn_cvt_pk_f32_fp8(w8[v][p].y, false);
      vf2 a3 = __builtin_amdgcn_cvt_pk_f32_fp8(w8[v][p].y, true);
      lacc[0] += axp * a0.x; lacc[1] += axp * a0.y;
      lacc[2] += axp * a1.x; lacc[3] += axp * a1.y;
      lacc[4] += axp * a2.x; lacc[5] += axp * a2.y;
      lacc[6] += axp * a3.x; lacc[7] += axp * a3.y;
    }
#pragma unroll
    for (int off = 8; off; off >>= 1) {
#pragma unroll
      for (int j = 0; j < 8; ++j) lacc[j] += __shfl_xor(lacc[j], off);
    }
    lacc[0] = lacc[0] * 0.015625f + wbe.x; lacc[1] = lacc[1] * 0.015625f + wbo.x;
    lacc[2] = lacc[2] * 0.015625f + wbe.y; lacc[3] = lacc[3] * 0.015625f + wbo.y;
    lacc[4] = lacc[4] * 0.015625f + wbe.z; lacc[5] = lacc[5] * 0.015625f + wbo.z;
    lacc[6] = lacc[6] * 0.015625f + wbe.w; lacc[7] = lacc[7] * 0.015625f + wbo.w;

    float mk = lacc[0];
#pragma unroll
    for (int j = 1; j < 8; ++j) mk = fmaxf(mk, lacc[j]);
    mk = fmaxf(mk, __shfl_xor(mk, 16));
    mk = fmaxf(mk, __shfl_xor(mk, 32));
    float ek[8], sk = 0.f;
#pragma unroll
    for (int j = 0; j < 8; ++j) { ek[j] = __expf(lacc[j] - mk); sk += ek[j]; }
    sk += __shfl_xor(sk, 16);
    sk += __shfl_xor(sk, 32);
    float inv = 1.0f / sk;

    if (g == 0) {
      float4 o0, o1;
      o0.x = ek[0] * inv; o0.y = ek[1] * inv; o0.z = ek[2] * inv; o0.w = ek[3] * inv;
      o1.x = ek[4] * inv; o1.y = ek[5] * inv; o1.z = ek[6] * inv; o1.w = ek[7] * inv;
      float* dst = pOut + (size_t)r * 32 + sub * 8;
      stnt_f4(dst, o0);
      stnt_f4(dst + 4, o1);
    }
  }
}

// ---------------- k4: pool permuted p over contiguous segments, apply Tw/Tb, dot.
__global__ __launch_bounds__(256) void k4_final(
    const float* __restrict__ p, const int* __restrict__ uidx,
    const int* __restrict__ iidx, const int* __restrict__ user,
    const int* __restrict__ item, const float* __restrict__ uemb,
    const float* __restrict__ iemb, const float* __restrict__ Tw,
    const float* __restrict__ Tb, const float* __restrict__ avg,
    float* __restrict__ out, int B, int per) {
  int t = threadIdx.x;
  int w = t >> 6, lane = t & 63;
  int b = blockIdx.x * 4 + w;
  if (b >= B) return;

  int idx = lane & 31;
  const int* sidx = (lane < 32) ? uidx : iidx;
  float pbar = 0.f;
  int base = b * per;
  for (int j = 0; j < per; ++j) {
    int id = sidx[base + j];
    pbar += p[(size_t)id * 32 + idx];
  }
  pbar *= 1.0f / (float)per;

  const float2* T2 = (const float2*)Tw;
  float2 tb2 = ((const float2*)Tb)[lane];
  float2 ua = tb2, ia = tb2;
#pragma unroll 8
  for (int kk = 0; kk < 32; ++kk) {
    int ka = ((kk & 1) << 4) + ((kk >> 3) << 2) + ((kk & 7) >> 1);
    float pu = __shfl(pbar, kk);
    float pi = __shfl(pbar, 32 + kk);
    float2 tv = T2[ka * 64 + lane];
    ua.x += pu * tv.x; ua.y += pu * tv.y;
    ia.x += pi * tv.x; ia.y += pi * tv.y;
  }
  float part = ua.x * ia.x + ua.y * ia.y;
  float2 uf = ((const float2*)uemb)[(size_t)user[b] * 64 + lane];
  float2 itf = ((const float2*)iemb)[(size_t)item[b] * 64 + lane];
  part += uf.x * itf.x + uf.y * itf.y;
#pragma unroll
  for (int off = 32; off; off >>= 1) part += __shfl_xor(part, off);
  if (lane == 0) out[b] = part + avg[0];
}

extern "C" void kernel_launch(void* const* d_in, const int* in_sizes, int n_in,
                              void* d_out, int out_size, void* d_ws, size_t ws_size,
                              hipStream_t stream) {
  const int*   user = (const int*)d_in[0];
  const int*   item = (const int*)d_in[1];
  const int*   hr   = (const int*)d_in[2];
  const float* Y    = (const float*)d_in[3];
  const int*   uhi  = (const int*)d_in[4];
  const int*   ihi  = (const int*)d_in[6];
  const float* We   = (const float*)d_in[8];
  const float* Mw   = (const float*)d_in[9];
  // d_in[10]: M_b — softmax-invariant, dropped
  const float* Ww   = (const float*)d_in[11];
  const float* Wb   = (const float*)d_in[12];
  const float* Tw   = (const float*)d_in[13];
  const float* Tb   = (const float*)d_in[14];
  const float* Ue   = (const float*)d_in[15];
  const float* Ie   = (const float*)d_in[16];
  const float* avg  = (const float*)d_in[17];

  int B = in_sizes[0];
  int R = in_sizes[3] / 128;
  int V = in_sizes[8] / 128;
  int L = in_sizes[4];
  int per = L / B;

  // Host always reserves the larger (fp8) Z footprint; device may use only V*64.
  unsigned char* ws = (unsigned char*)d_ws;
  uint4* Wpk = (uint4*)ws;                               // 40 KB
  unsigned char* Z   = ws + 40960;                       // <= V*128
  unsigned char* WW8 = Z + (size_t)V * 128;              // V*32
  float* Yp   = (float*)(WW8 + (size_t)V * 32);          // R*128 floats
  float* pbuf = Yp + (size_t)R * 128;                    // R*32 floats
  float* out = (float*)d_out;

  kA0_pack<<<10, 256, 0, stream>>>(Mw, Ww, Wpk);
  kY_perm<<<(R * 128 + 255) / 256, 256, 0, stream>>>(Y, Yp, R * 128);
  kA_mfma<<<(V + 63) / 64, 256, 0, stream>>>(We, Wpk, Z, WW8, V);
  k3_review<<<(R + 7) / 8, 256, 0, stream>>>(hr, Yp, Z, WW8, Wb, pbuf, R);
  k4_final<<<(B + 3) / 4, 256, 0, stream>>>(pbuf, uhi, ihi, user, item, Ue, Ie,
                                            Tw, Tb, avg, out, B, per);
}